// Round 8
// baseline (963.830 us; speedup 1.0000x reference)
//
#include <hip/hip_runtime.h>

// DeepCNF: 5x conv1d(K=11)+tanh -> 1x1 conv to 8 tags -> CRF NLL (sum over batch).
// B=128 T=1024 IN=42 HID=256 K=11 NTAGS=8.
// Inter-layer H: bf16, row=(b*T+t)*256 shorts, 16B chunks at (chunk ^ (t&7)).
// Mid convs: round-3 occupancy structure (128t x 256co, 8 waves = wr x wc,
// 70.6KB LDS, 2 blocks/CU, 4 waves/SIMD) but with 32x32x16 MFMA (higher
// ceiling, half the instructions). Wave tile 64t x 64co = acc[2][2] f32x16.
// A: row=l&31, k=(l>>5)*8+e.  B: col=l&31, k=(l>>5)*8+e.
// C/D: col=l&31, row=(reg&3)+8*(reg>>2)+4*(l>>5)  [m74/m101 verified].
// Waves stagger their cic start by wc*2 to decorrelate matrix-pipe phases;
// B prefetch wraps within the layer table. conv4 fuses emissions (LDS
// partial reduce). CRF: log-semiring segment products (32 segs of 32).

#define B_ 128
#define T_ 1024
#define IN_DIM_ 42
#define HID_ 256
#define KW_ 11
#define NTAGS_ 8
#define SEG_ 32
#define SEGL_ (T_ / SEG_)   // 32

typedef __bf16 bf16x8 __attribute__((ext_vector_type(8)));
typedef float f32x4 __attribute__((ext_vector_type(4)));
typedef float f32x16 __attribute__((ext_vector_type(16)));
typedef short s16x8 __attribute__((ext_vector_type(8)));

__device__ __forceinline__ unsigned short f2bf(float f) {
    unsigned u = __builtin_bit_cast(unsigned, f);
    u += 0x7FFFu + ((u >> 16) & 1u);   // RNE
    return (unsigned short)(u >> 16);
}
__device__ __forceinline__ float fast_tanh(float x) {
    float e = __expf(2.f * x);          // inf/0 saturate to +-1 correctly
    return 1.f - 2.f / (e + 1.f);
}

#define SZ0_ (KW_ * 2 * 16 * 512)   // layer0 table (16x16 frags, k-major)
#define SZN_ (KW_ * 8 * 16 * 512)   // layers1-4 tables (32x32 frags)

// ---------------------------------------------------------------------------
// Pack all conv weights fp32 -> bf16 MFMA B-fragments.
// Layer 0 (16x16 frags, k-major it2 = k*2+cic):
//   wp[((it2*16+coc)*64+lane)*8+e] = w[coc*16+(l&15)][cic*32+(l>>4)*8+e][k]
// Layers 1-4 (32x32 frags, it = cic*11+k, ksub, coltile):
//   wp[(((it*2+ksub)*8+coltile)*64+lane)*8+e] =
//     w[coltile*32+(l&31)][cic*32+ksub*16+(l>>5)*8+e][k]
// ---------------------------------------------------------------------------
__global__ void pack_all(const float* __restrict__ w0, const float* __restrict__ w1,
                         const float* __restrict__ w2, const float* __restrict__ w3,
                         const float* __restrict__ w4, unsigned short* __restrict__ wp) {
    const int total = SZ0_ + 4 * SZN_;
    for (int idx = blockIdx.x * 256 + threadIdx.x; idx < total;
         idx += gridDim.x * 256) {
        float v;
        if (idx < SZ0_) {
            int loc = idx;
            int it2 = loc >> 13;
            int cic = it2 & 1, k = it2 >> 1;
            int e    = loc & 7;
            int lane = (loc >> 3) & 63;
            int coc  = (loc >> 9) & 15;
            int co = coc * 16 + (lane & 15);
            int ci = cic * 32 + ((lane >> 4) & 3) * 8 + e;
            v = (ci < IN_DIM_) ? w0[(co * IN_DIM_ + ci) * KW_ + k] : 0.f;
        } else {
            int r = idx - SZ0_;
            int L = r / SZN_;
            int loc = r - L * SZN_;
            const float* w = (L == 0) ? w1 : (L == 1) ? w2 : (L == 2) ? w3 : w4;
            int e       = loc & 7;
            int lane    = (loc >> 3) & 63;
            int coltile = (loc >> 9) & 7;
            int g       = loc >> 12;          // it*2 + ksub
            int ksub    = g & 1;
            int it      = g >> 1;
            int cic     = it / KW_;
            int k       = it - cic * KW_;
            int co = coltile * 32 + (lane & 31);
            int ci = cic * 32 + ksub * 16 + (lane >> 5) * 8 + e;
            v = w[(co * HID_ + ci) * KW_ + k];
        }
        wp[idx] = f2bf(v);
    }
}

// ---------------------------------------------------------------------------
// First conv layer: fp32 x (42ch) input, 128t x 256co block, 8 waves
// (2 t-halves x 4 co-quarters), 16x16x32 MFMA, CIN padded to 64.
// ---------------------------------------------------------------------------
__global__ __launch_bounds__(512, 4)
void conv_first(const float* __restrict__ x, const unsigned short* __restrict__ wpack,
                const float* __restrict__ bias, unsigned short* __restrict__ out) {
    constexpr int CIN = 64, ROWS = 138;
    __shared__ unsigned short lds[ROWS * CIN];

    const int tid  = threadIdx.x;
    const int wave = tid >> 6;
    const int lane = tid & 63;
    const int l15  = lane & 15;
    const int lhi  = lane >> 4;
    const int wr   = wave >> 2;
    const int wc   = wave & 3;
    const int b    = blockIdx.x >> 3;
    const int t0   = (blockIdx.x & 7) * 128;

    for (int u = tid; u < ROWS * 32; u += 512) {
        int r = u >> 5, m = u & 31;        // m = float2 index, ci0 = 2m
        int gt = t0 - 5 + r;
        unsigned val = 0;
        if (gt >= 0 && gt < T_ && 2 * m < IN_DIM_) {
            float2 f = *(const float2*)&x[((size_t)b * T_ + gt) * IN_DIM_ + 2 * m];
            val = (unsigned)f2bf(f.x) | ((unsigned)f2bf(f.y) << 16);
        }
        int c = m >> 2;
        int p = c ^ ((r + 3) & 7);
        ((unsigned*)lds)[(r * CIN + p * 8) / 2 + (m & 3)] = val;
    }
    __syncthreads();

    f32x4 acc[4][4];
#pragma unroll
    for (int tf = 0; tf < 4; ++tf)
#pragma unroll
        for (int n = 0; n < 4; ++n) acc[tf][n] = (f32x4){0.f, 0.f, 0.f, 0.f};

    const unsigned short* wpq = wpack + (size_t)(wc * 4) * 512 + lane * 8;
    const int arow = (wr * 64 + l15) * CIN;
    const int l153 = l15 + 3;

    s16x8 Bq[2][4];
#pragma unroll
    for (int n = 0; n < 4; ++n) Bq[0][n] = *(const s16x8*)&wpq[n * 512];

#pragma unroll
    for (int k = 0; k < KW_; ++k) {
#pragma unroll
        for (int cic = 0; cic < 2; ++cic) {
            const int it2 = k * 2 + cic;
            const int nxt = it2 + 1;       // overrun into next table: harmless
#pragma unroll
            for (int n = 0; n < 4; ++n)
                Bq[nxt & 1][n] = *(const s16x8*)&wpq[(size_t)nxt * 8192 + n * 512];
            const int key = (l153 + k) & 7;
            const int ao  = arow + (((cic * 4 + lhi) ^ key) << 3);
            s16x8 a0 = *(const s16x8*)&lds[ao + (0 * 16 + k) * CIN];
            s16x8 a1 = *(const s16x8*)&lds[ao + (1 * 16 + k) * CIN];
            s16x8 a2 = *(const s16x8*)&lds[ao + (2 * 16 + k) * CIN];
            s16x8 a3 = *(const s16x8*)&lds[ao + (3 * 16 + k) * CIN];
            __builtin_amdgcn_s_setprio(1);
#pragma unroll
            for (int n = 0; n < 4; ++n) {
                bf16x8 bb = __builtin_bit_cast(bf16x8, Bq[it2 & 1][n]);
                acc[0][n] = __builtin_amdgcn_mfma_f32_16x16x32_bf16(
                    __builtin_bit_cast(bf16x8, a0), bb, acc[0][n], 0, 0, 0);
                acc[1][n] = __builtin_amdgcn_mfma_f32_16x16x32_bf16(
                    __builtin_bit_cast(bf16x8, a1), bb, acc[1][n], 0, 0, 0);
                acc[2][n] = __builtin_amdgcn_mfma_f32_16x16x32_bf16(
                    __builtin_bit_cast(bf16x8, a2), bb, acc[2][n], 0, 0, 0);
                acc[3][n] = __builtin_amdgcn_mfma_f32_16x16x32_bf16(
                    __builtin_bit_cast(bf16x8, a3), bb, acc[3][n], 0, 0, 0);
            }
            __builtin_amdgcn_s_setprio(0);
        }
    }

#pragma unroll
    for (int n = 0; n < 4; ++n) {
        int co = wc * 64 + n * 16 + l15;
        float bv = bias[co];
#pragma unroll
        for (int tf = 0; tf < 4; ++tf) {
#pragma unroll
            for (int r4 = 0; r4 < 4; ++r4) {
                int t = t0 + wr * 64 + tf * 16 + lhi * 4 + r4;
                float v = fast_tanh(acc[tf][n][r4] + bv);
                int pos = (co >> 3) ^ (t & 7);
                out[((size_t)b * T_ + t) * HID_ + pos * 8 + (co & 7)] = f2bf(v);
            }
        }
    }
}

// ---------------------------------------------------------------------------
// Mid conv: 128t x 256co block, 8 waves (wr t-half x wc co-quarter),
// wave tile 64t x 64co via 32x32x16 MFMA: acc[2][2] f32x16.
// cic start staggered by wc*2; B depth-1 register prefetch (parity slots).
// LAST: fused emission projection via LDS partial reduce (no atomics).
// ---------------------------------------------------------------------------
template <bool LAST>
__global__ __launch_bounds__(512, 4)
void conv_mid(const unsigned short* __restrict__ Hin,
              const unsigned short* __restrict__ wpack,
              const float* __restrict__ bias, unsigned short* __restrict__ out,
              const float* __restrict__ w_out, float* __restrict__ emout) {
    constexpr int CIN = 256, ROWS = 138;
    extern __shared__ unsigned short lds[];   // [138][256] = 70656 B

    const int tid  = threadIdx.x;
    const int wave = tid >> 6;
    const int lane = tid & 63;
    const int l31  = lane & 31;
    const int lh   = lane >> 5;
    const int wr   = wave >> 2;               // t-half (64)
    const int wc   = wave & 3;                // co-quarter (64)
    const int b    = blockIdx.x >> 3;
    const int t0   = (blockIdx.x & 7) * 128;

    // ---- stage rows [t0-5, t0+133) (clamped; halo zeroed below) ----
    for (int r0 = wave * 2; r0 < ROWS; r0 += 16) {
        int r  = r0 + (lane >> 5);
        int gt = t0 - 5 + r;
        gt = gt < 0 ? 0 : (gt >= T_ ? T_ - 1 : gt);
        const unsigned short* src =
            Hin + ((size_t)b * T_ + gt) * CIN + (lane & 31) * 8;
        __builtin_amdgcn_global_load_lds(
            (const __attribute__((address_space(1))) void*)src,
            (__attribute__((address_space(3))) void*)&lds[r0 * CIN], 16, 0, 0);
    }
    __syncthreads();
    if (t0 == 0) {
        for (int u = tid; u < 5 * (CIN / 2); u += 512)
            ((unsigned*)lds)[u] = 0;                       // rows 0..4
    }
    if (t0 == T_ - 128) {
        for (int u = tid; u < 5 * (CIN / 2); u += 512)
            ((unsigned*)&lds[133 * CIN])[u] = 0;           // rows 133..137
    }
    __syncthreads();

    f32x16 acc[2][2];
#pragma unroll
    for (int rt = 0; rt < 2; ++rt)
#pragma unroll
        for (int ct = 0; ct < 2; ++ct)
#pragma unroll
            for (int e = 0; e < 16; ++e) acc[rt][ct][e] = 0.f;

    // B frag (it, ksub, ct) at wpB + it*8192 + ksub*4096 + ct*512 (shorts)
    const unsigned short* wpB = wpack + (size_t)(wc * 2) * 512 + lane * 8;
    const int arow0 = (wr * 64 + l31) * CIN;   // rt=0 row base (shorts)
    const int l313  = l31 + 3;

    s16x8 Bq[2][2][2];                         // [parity][ksub][ct]
    {
        const int it0 = wc * 2 * KW_;          // staggered start cic = wc*2
#pragma unroll
        for (int ks = 0; ks < 2; ++ks)
#pragma unroll
            for (int ct = 0; ct < 2; ++ct)
                Bq[0][ks][ct] = *(const s16x8*)&wpB[(size_t)it0 * 8192 +
                                                    ks * 4096 + ct * 512];
    }

#pragma unroll 1
    for (int cv = 0; cv < 8; cv += 2) {
        int c0 = cv + wc * 2;
        if (c0 >= 8) c0 -= 8;                  // even, <=6; c1 = c0+1 in range
        const int itb0 = c0 * KW_;
        const int itb1 = itb0 + KW_;
        const int cq0  = c0 * 4 + lh;          // A chunk base for cic=c0
        int c2 = c0 + 2;
        if (c2 >= 8) c2 -= 8;
        const int itb2 = c2 * KW_;             // next cv's first it (wraps)
#pragma unroll
        for (int kk = 0; kk < 2 * KW_; ++kk) {
            const int k   = (kk < KW_) ? kk : kk - KW_;
            const int cq  = (kk < KW_) ? cq0 : cq0 + 4;
            // prefetch pos+1 (wraps within the table; last one feeds next cv)
            const int itn = (kk < KW_ - 1)     ? itb0 + kk + 1
                            : (kk == KW_ - 1)  ? itb1
                            : (kk < 2 * KW_ - 1) ? itb1 + (kk - KW_) + 1
                                                 : itb2;
#pragma unroll
            for (int ks = 0; ks < 2; ++ks)
#pragma unroll
                for (int ct = 0; ct < 2; ++ct)
                    Bq[(kk + 1) & 1][ks][ct] =
                        *(const s16x8*)&wpB[(size_t)itn * 8192 + ks * 4096 +
                                            ct * 512];
            // A reads: 2 chunk addrs, rt via ds-offset immediates
            const int key = (l313 + k) & 7;
            const int a0  = arow0 + ((cq ^ key) << 3);
            const int a1  = arow0 + (((cq + 2) ^ key) << 3);
            s16x8 A00 = *(const s16x8*)&lds[a0 + k * CIN];            // rt0 ks0
            s16x8 A01 = *(const s16x8*)&lds[a1 + k * CIN];            // rt0 ks1
            s16x8 A10 = *(const s16x8*)&lds[a0 + (32 + k) * CIN];     // rt1 ks0
            s16x8 A11 = *(const s16x8*)&lds[a1 + (32 + k) * CIN];     // rt1 ks1
            __builtin_amdgcn_s_setprio(1);
#pragma unroll
            for (int ct = 0; ct < 2; ++ct) {
                bf16x8 b0 = __builtin_bit_cast(bf16x8, Bq[kk & 1][0][ct]);
                bf16x8 b1 = __builtin_bit_cast(bf16x8, Bq[kk & 1][1][ct]);
                acc[0][ct] = __builtin_amdgcn_mfma_f32_32x32x16_bf16(
                    __builtin_bit_cast(bf16x8, A00), b0, acc[0][ct], 0, 0, 0);
                acc[1][ct] = __builtin_amdgcn_mfma_f32_32x32x16_bf16(
                    __builtin_bit_cast(bf16x8, A10), b0, acc[1][ct], 0, 0, 0);
                acc[0][ct] = __builtin_amdgcn_mfma_f32_32x32x16_bf16(
                    __builtin_bit_cast(bf16x8, A01), b1, acc[0][ct], 0, 0, 0);
                acc[1][ct] = __builtin_amdgcn_mfma_f32_32x32x16_bf16(
                    __builtin_bit_cast(bf16x8, A11), b1, acc[1][ct], 0, 0, 0);
            }
            __builtin_amdgcn_s_setprio(0);
        }
    }

    if constexpr (!LAST) {
        // epilogue: bias + tanh -> bf16, stored chunk-swizzled by (t&7).
        // C/D: col = l31 (co), row = (reg&3) + 8*(reg>>2) + 4*lh (t).
#pragma unroll
        for (int ct = 0; ct < 2; ++ct) {
            int co = wc * 64 + ct * 32 + l31;
            float bv = bias[co];
            int cobase = (co >> 3);
#pragma unroll
            for (int rt = 0; rt < 2; ++rt) {
#pragma unroll
                for (int reg = 0; reg < 16; ++reg) {
                    int t = t0 + wr * 64 + rt * 32 + (reg & 3) + 8 * (reg >> 2) +
                            4 * lh;
                    float v = fast_tanh(acc[rt][ct][reg] + bv);
                    int pos = cobase ^ (t & 7);
                    out[((size_t)b * T_ + t) * HID_ + pos * 8 + (co & 7)] = f2bf(v);
                }
            }
        }
    } else {
        // fused emissions: reduce h*w_out over co (32-lane shfl_xor within
        // each half, halves hold different t) -> LDS partials -> block reduce.
        float wv[2][NTAGS_], bv[2];
#pragma unroll
        for (int ct = 0; ct < 2; ++ct) {
            int co = wc * 64 + ct * 32 + l31;
            bv[ct] = bias[co];
#pragma unroll
            for (int tg = 0; tg < NTAGS_; ++tg) wv[ct][tg] = w_out[tg * HID_ + co];
        }
        __syncthreads();                 // A-tile reads done; reuse LDS
        float* pbuf = (float*)lds;       // [4 wc][128 t][8 tg] = 16 KB
#pragma unroll
        for (int rt = 0; rt < 2; ++rt) {
#pragma unroll
            for (int reg = 0; reg < 16; ++reg) {
                float h0 = fast_tanh(acc[rt][0][reg] + bv[0]);
                float h1 = fast_tanh(acc[rt][1][reg] + bv[1]);
                float pt[NTAGS_];
#pragma unroll
                for (int tg = 0; tg < NTAGS_; ++tg)
                    pt[tg] = h0 * wv[0][tg] + h1 * wv[1][tg];
#pragma unroll
                for (int off = 16; off; off >>= 1)
#pragma unroll
                    for (int tg = 0; tg < NTAGS_; ++tg)
                        pt[tg] += __shfl_xor(pt[tg], off);
                if (l31 == 0) {
                    int tloc = wr * 64 + rt * 32 + (reg & 3) + 8 * (reg >> 2) +
                               4 * lh;
                    f32x4 lo = {pt[0], pt[1], pt[2], pt[3]};
                    f32x4 hi = {pt[4], pt[5], pt[6], pt[7]};
                    *(f32x4*)&pbuf[(wc * 128 + tloc) * 8]     = lo;
                    *(f32x4*)&pbuf[(wc * 128 + tloc) * 8 + 4] = hi;
                }
            }
        }
        __syncthreads();
        for (int u = tid; u < 128 * NTAGS_; u += 512) {
            float s = pbuf[u] + pbuf[1024 + u] + pbuf[2048 + u] + pbuf[3072 + u];
            emout[((size_t)b * T_ + t0) * NTAGS_ + u] = s;
        }
    }
}

// ---------------------------------------------------------------------------
// CRF segment kernel: wave per (b, s). Lane (i=lane>>3, j=lane&7) holds
// M[i][j], lse-product of S_t[i][j] = tr[i][j] + em[b,t,j] + bo[j].
// ---------------------------------------------------------------------------
__global__ __launch_bounds__(256)
void crf_seg_kernel(const float* __restrict__ em, const float* __restrict__ tr,
                    const float* __restrict__ bo, float* __restrict__ segM) {
    const int gw   = blockIdx.x * 4 + (threadIdx.x >> 6);
    const int b    = gw >> 5;
    const int s    = gw & 31;
    const int lane = threadIdx.x & 63;
    const int i    = lane >> 3;
    const int j    = lane & 7;
    const float* emb = em + (size_t)b * T_ * NTAGS_;
    const float boj = bo[j];

    float tc[8];
#pragma unroll
    for (int k = 0; k < 8; ++k) tc[k] = tr[k * 8 + j];

    const int tb = (s == 0) ? 1 : s * SEGL_;
    const int te = (s + 1) * SEGL_;

    float m = tr[i * 8 + j] + emb[tb * 8 + j] + boj;
    for (int t = tb + 1; t < te; ++t) {
        float emt = emb[t * 8 + j] + boj;
        float v[8];
#pragma unroll
        for (int k = 0; k < 8; ++k) v[k] = __shfl(m, (lane & 56) + k) + tc[k];
        float mx = fmaxf(fmaxf(fmaxf(v[0], v[1]), fmaxf(v[2], v[3])),
                         fmaxf(fmaxf(v[4], v[5]), fmaxf(v[6], v[7])));
        float sm = 0.f;
#pragma unroll
        for (int k = 0; k < 8; ++k) sm += __expf(v[k] - mx);
        m = mx + __logf(sm) + emt;
    }
    segM[(size_t)gw * 64 + lane] = m;
}

// ---------------------------------------------------------------------------
// CRF combine: one wave per batch. Numerator + 32-segment fold.
// ---------------------------------------------------------------------------
__global__ __launch_bounds__(64)
void crf_kernel(const float* __restrict__ em, const float* __restrict__ segM,
                const int* __restrict__ tags,
                const float* __restrict__ st, const float* __restrict__ et,
                const float* __restrict__ tr, const float* __restrict__ bo,
                float* __restrict__ outp) {
    __shared__ float sM[SEG_ * 64];
    const int b    = blockIdx.x;
    const int lane = threadIdx.x;
    const float* emb = em + (size_t)b * T_ * NTAGS_;
    const int*   tg  = tags + (size_t)b * T_;

    for (int u = lane; u < SEG_ * 64; u += 64)
        sM[u] = segM[(size_t)b * SEG_ * 64 + u];

    const float breg = bo[lane & 7];

    float num = 0.f;
    for (int t = 1 + lane; t < T_; t += 64) {
        int pt = tg[t - 1], ct = tg[t];
        num += tr[pt * NTAGS_ + ct] + emb[t * NTAGS_ + ct] + __shfl(breg, ct);
    }
#pragma unroll
    for (int off = 32; off; off >>= 1) num += __shfl_down(num, off);
    int tgf = tg[0], tgl = tg[T_ - 1];
    float bo_f = __shfl(breg, tgf);
    float score = 0.f;
    if (lane == 0)
        score = num + st[tgf] + emb[tgf] + bo_f + et[tgl];

    __syncthreads();

    const int j = lane & 7;
    float alpha = st[j] + emb[j] + breg;
    for (int sgm = 0; sgm < SEG_; ++sgm) {
        const float* M = &sM[sgm * 64];
        float v[8];
#pragma unroll
        for (int i = 0; i < 8; ++i) v[i] = __shfl(alpha, i) + M[i * 8 + j];
        float mx = fmaxf(fmaxf(fmaxf(v[0], v[1]), fmaxf(v[2], v[3])),
                         fmaxf(fmaxf(v[4], v[5]), fmaxf(v[6], v[7])));
        float sm = 0.f;
#pragma unroll
        for (int i = 0; i < 8; ++i) sm += __expf(v[i] - mx);
        alpha = mx + __logf(sm);
    }
    float vj = alpha + et[j];
    float w[8];
#pragma unroll
    for (int i = 0; i < 8; ++i) w[i] = __shfl(vj, i);
    float m2 = w[0];
#pragma unroll
    for (int i = 1; i < 8; ++i) m2 = fmaxf(m2, w[i]);
    float s2 = 0.f;
#pragma unroll
    for (int i = 0; i < 8; ++i) s2 += __expf(w[i] - m2);
    float log_z = m2 + __logf(s2);

    if (lane == 0) atomicAdd(outp, log_z - score);
}

// ---------------------------------------------------------------------------
extern "C" void kernel_launch(void* const* d_in, const int* in_sizes, int n_in,
                              void* d_out, int out_size, void* d_ws, size_t ws_size,
                              hipStream_t stream) {
    const float* x     = (const float*)d_in[0];
    const int*   tags  = (const int*)d_in[3];
    const float* w[5]  = {(const float*)d_in[4], (const float*)d_in[6],
                          (const float*)d_in[8], (const float*)d_in[10],
                          (const float*)d_in[12]};
    const float* bias[5] = {(const float*)d_in[5], (const float*)d_in[7],
                            (const float*)d_in[9], (const float*)d_in[11],
                            (const float*)d_in[13]};
    const float* w_out = (const float*)d_in[14];
    const float* b_out = (const float*)d_in[15];
    const float* st    = (const float*)d_in[16];
    const float* et    = (const float*)d_in[17];
    const float* tr    = (const float*)d_in[18];

    // workspace layout: H0, H1, wp tables, em, segM
    unsigned short* H0 = (unsigned short*)d_ws;
    unsigned short* H1 = H0 + (size_t)B_ * T_ * HID_;
    unsigned short* wpbase = H1 + (size_t)B_ * T_ * HID_;
    unsigned short* wp[5];
    wp[0] = wpbase;
    wp[1] = wp[0] + SZ0_;
    wp[2] = wp[1] + SZN_;
    wp[3] = wp[2] + SZN_;
    wp[4] = wp[3] + SZN_;
    float* em   = (float*)(wp[4] + SZN_);
    float* segM = em + (size_t)B_ * T_ * NTAGS_;
    // conv_first B-prefetch overruns its table into wp[1] (harmless reads);
    // mid conv prefetch wraps within its own table (stagger) -- no overrun.

    const int MLDS = 138 * 256 * 2;   // 70656 B dynamic LDS for mid convs
    hipFuncSetAttribute((const void*)conv_mid<false>,
                        hipFuncAttributeMaxDynamicSharedMemorySize, MLDS);
    hipFuncSetAttribute((const void*)conv_mid<true>,
                        hipFuncAttributeMaxDynamicSharedMemorySize, MLDS);

    pack_all<<<2048, 256, 0, stream>>>(w[0], w[1], w[2], w[3], w[4], wpbase);

    const int NBLK = B_ * (T_ / 128);   // 1024
    conv_first<<<NBLK, 512, 0, stream>>>(x, wp[0], bias[0], H0);

    conv_mid<false><<<NBLK, 512, MLDS, stream>>>(H0, wp[1], bias[1], H1,
                                                 nullptr, nullptr);
    conv_mid<false><<<NBLK, 512, MLDS, stream>>>(H1, wp[2], bias[2], H0,
                                                 nullptr, nullptr);
    conv_mid<false><<<NBLK, 512, MLDS, stream>>>(H0, wp[3], bias[3], H1,
                                                 nullptr, nullptr);
    conv_mid<true><<<NBLK, 512, MLDS, stream>>>(H1, wp[4], bias[4], nullptr,
                                                w_out, em);

    crf_seg_kernel<<<B_ * SEG_ / 4, 256, 0, stream>>>(em, tr, b_out, segM);

    hipMemsetAsync(d_out, 0, sizeof(float), stream);
    crf_kernel<<<B_, 64, 0, stream>>>(em, segM, tags, st, et, tr, b_out,
                                      (float*)d_out);
}

// Round 9
// 769.700 us; speedup vs baseline: 1.2522x; 1.2522x over previous
//
#include <hip/hip_runtime.h>

// DeepCNF: 5x conv1d(K=11)+tanh -> 1x1 conv to 8 tags -> CRF NLL (sum over batch).
// B=128 T=1024 IN=42 HID=256 K=11 NTAGS=8.
// Consolidated best-of: round-7 conv_first + round-3 mid conv (128t x 256co,
// 8 waves, 16x16x32 MFMA, distance-16 MFMA clusters, depth-1 B prefetch)
// + fused emission epilogue on the last layer (LDS partial reduce, no atomics)
// + log-semiring segmented CRF.
// Inter-layer H: bf16, row=(b*T+t)*256 shorts, 16B chunks at (chunk ^ (t&7)).

#define B_ 128
#define T_ 1024
#define IN_DIM_ 42
#define HID_ 256
#define KW_ 11
#define NTAGS_ 8
#define SEG_ 32
#define SEGL_ (T_ / SEG_)   // 32

typedef __bf16 bf16x8 __attribute__((ext_vector_type(8)));
typedef float f32x4 __attribute__((ext_vector_type(4)));
typedef short s16x8 __attribute__((ext_vector_type(8)));

__device__ __forceinline__ unsigned short f2bf(float f) {
    unsigned u = __builtin_bit_cast(unsigned, f);
    u += 0x7FFFu + ((u >> 16) & 1u);   // RNE
    return (unsigned short)(u >> 16);
}
__device__ __forceinline__ float fast_tanh(float x) {
    float e = __expf(2.f * x);          // inf/0 saturate to +-1 correctly
    return 1.f - 2.f / (e + 1.f);
}

#define SZ0_ (KW_ * 2 * 16 * 512)   // layer0 table (16x16 frags, k-major)
#define SZN_ (KW_ * 8 * 16 * 512)   // layers1-4 tables (16x16 frags, cic-major)

// ---------------------------------------------------------------------------
// Pack all conv weights fp32 -> bf16 16x16-MFMA B-fragments.
// Layer 0 (k-major, it2 = k*2+cic, as conv_first consumes):
//   wp[((it2*16+coc)*64+lane)*8+e] = w0[coc*16+(l&15)][cic*32+(l>>4)*8+e][k]
// Layers 1-4 (cic-major, it = cic*11+k, as conv_mid consumes):
//   wp[((it*16+coc)*64+lane)*8+e]  = w[coc*16+(l&15)][cic*32+(l>>4)*8+e][k]
// ---------------------------------------------------------------------------
__global__ void pack_all(const float* __restrict__ w0, const float* __restrict__ w1,
                         const float* __restrict__ w2, const float* __restrict__ w3,
                         const float* __restrict__ w4, unsigned short* __restrict__ wp) {
    const int total = SZ0_ + 4 * SZN_;
    for (int idx = blockIdx.x * 256 + threadIdx.x; idx < total;
         idx += gridDim.x * 256) {
        float v;
        if (idx < SZ0_) {
            int loc = idx;
            int it2 = loc >> 13;
            int cic = it2 & 1, k = it2 >> 1;
            int e    = loc & 7;
            int lane = (loc >> 3) & 63;
            int coc  = (loc >> 9) & 15;
            int co = coc * 16 + (lane & 15);
            int ci = cic * 32 + ((lane >> 4) & 3) * 8 + e;
            v = (ci < IN_DIM_) ? w0[(co * IN_DIM_ + ci) * KW_ + k] : 0.f;
        } else {
            int r = idx - SZ0_;
            int L = r / SZN_;
            int loc = r - L * SZN_;
            const float* w = (L == 0) ? w1 : (L == 1) ? w2 : (L == 2) ? w3 : w4;
            int e    = loc & 7;
            int lane = (loc >> 3) & 63;
            int coc  = (loc >> 9) & 15;
            int rest = loc >> 13;          // it = cic*KW_ + k
            int cic  = rest / KW_;
            int k    = rest - cic * KW_;
            int co = coc * 16 + (lane & 15);
            int ci = cic * 32 + ((lane >> 4) & 3) * 8 + e;
            v = w[(co * HID_ + ci) * KW_ + k];
        }
        wp[idx] = f2bf(v);
    }
}

// ---------------------------------------------------------------------------
// First conv layer: fp32 x (42ch) input, 128t x 256co block, 8 waves
// (2 t-halves x 4 co-quarters), 16x16x32 MFMA, CIN padded to 64.
// ---------------------------------------------------------------------------
__global__ __launch_bounds__(512, 4)
void conv_first(const float* __restrict__ x, const unsigned short* __restrict__ wpack,
                const float* __restrict__ bias, unsigned short* __restrict__ out) {
    constexpr int CIN = 64, ROWS = 138;
    __shared__ unsigned short lds[ROWS * CIN];

    const int tid  = threadIdx.x;
    const int wave = tid >> 6;
    const int lane = tid & 63;
    const int l15  = lane & 15;
    const int lhi  = lane >> 4;
    const int wr   = wave >> 2;
    const int wc   = wave & 3;
    const int b    = blockIdx.x >> 3;
    const int t0   = (blockIdx.x & 7) * 128;

    for (int u = tid; u < ROWS * 32; u += 512) {
        int r = u >> 5, m = u & 31;        // m = float2 index, ci0 = 2m
        int gt = t0 - 5 + r;
        unsigned val = 0;
        if (gt >= 0 && gt < T_ && 2 * m < IN_DIM_) {
            float2 f = *(const float2*)&x[((size_t)b * T_ + gt) * IN_DIM_ + 2 * m];
            val = (unsigned)f2bf(f.x) | ((unsigned)f2bf(f.y) << 16);
        }
        int c = m >> 2;
        int p = c ^ ((r + 3) & 7);
        ((unsigned*)lds)[(r * CIN + p * 8) / 2 + (m & 3)] = val;
    }
    __syncthreads();

    f32x4 acc[4][4];
#pragma unroll
    for (int tf = 0; tf < 4; ++tf)
#pragma unroll
        for (int n = 0; n < 4; ++n) acc[tf][n] = (f32x4){0.f, 0.f, 0.f, 0.f};

    const unsigned short* wpq = wpack + (size_t)(wc * 4) * 512 + lane * 8;
    const int arow = (wr * 64 + l15) * CIN;
    const int l153 = l15 + 3;

    s16x8 Bq[2][4];
#pragma unroll
    for (int n = 0; n < 4; ++n) Bq[0][n] = *(const s16x8*)&wpq[n * 512];

#pragma unroll
    for (int k = 0; k < KW_; ++k) {
#pragma unroll
        for (int cic = 0; cic < 2; ++cic) {
            const int it2 = k * 2 + cic;
            const int nxt = it2 + 1;       // overrun into next table: harmless
#pragma unroll
            for (int n = 0; n < 4; ++n)
                Bq[nxt & 1][n] = *(const s16x8*)&wpq[(size_t)nxt * 8192 + n * 512];
            const int key = (l153 + k) & 7;
            const int ao  = arow + (((cic * 4 + lhi) ^ key) << 3);
            s16x8 a0 = *(const s16x8*)&lds[ao + (0 * 16 + k) * CIN];
            s16x8 a1 = *(const s16x8*)&lds[ao + (1 * 16 + k) * CIN];
            s16x8 a2 = *(const s16x8*)&lds[ao + (2 * 16 + k) * CIN];
            s16x8 a3 = *(const s16x8*)&lds[ao + (3 * 16 + k) * CIN];
            __builtin_amdgcn_s_setprio(1);
#pragma unroll
            for (int n = 0; n < 4; ++n) {
                bf16x8 bb = __builtin_bit_cast(bf16x8, Bq[it2 & 1][n]);
                acc[0][n] = __builtin_amdgcn_mfma_f32_16x16x32_bf16(
                    __builtin_bit_cast(bf16x8, a0), bb, acc[0][n], 0, 0, 0);
                acc[1][n] = __builtin_amdgcn_mfma_f32_16x16x32_bf16(
                    __builtin_bit_cast(bf16x8, a1), bb, acc[1][n], 0, 0, 0);
                acc[2][n] = __builtin_amdgcn_mfma_f32_16x16x32_bf16(
                    __builtin_bit_cast(bf16x8, a2), bb, acc[2][n], 0, 0, 0);
                acc[3][n] = __builtin_amdgcn_mfma_f32_16x16x32_bf16(
                    __builtin_bit_cast(bf16x8, a3), bb, acc[3][n], 0, 0, 0);
            }
            __builtin_amdgcn_s_setprio(0);
        }
    }

#pragma unroll
    for (int n = 0; n < 4; ++n) {
        int co = wc * 64 + n * 16 + l15;
        float bv = bias[co];
#pragma unroll
        for (int tf = 0; tf < 4; ++tf) {
#pragma unroll
            for (int r4 = 0; r4 < 4; ++r4) {
                int t = t0 + wr * 64 + tf * 16 + lhi * 4 + r4;
                float v = fast_tanh(acc[tf][n][r4] + bv);
                int pos = (co >> 3) ^ (t & 7);
                out[((size_t)b * T_ + t) * HID_ + pos * 8 + (co & 7)] = f2bf(v);
            }
        }
    }
}

// ---------------------------------------------------------------------------
// Mid conv (round-3 structure): 128t x 256co block, 8 waves = 2 t-halves x
// 4 co-quarters; wave tile 64t x 64co, 16x16x32 MFMA, 16 independent
// accumulators per cluster. Depth-1 B register prefetch.
// LAST: fused emission projection via LDS partial reduce (no atomics).
// ---------------------------------------------------------------------------
template <bool LAST>
__global__ __launch_bounds__(512, 4)
void conv_mid(const unsigned short* __restrict__ Hin,
              const unsigned short* __restrict__ wpack,
              const float* __restrict__ bias, unsigned short* __restrict__ out,
              const float* __restrict__ w_out, float* __restrict__ emout) {
    constexpr int CIN = 256, ROWS = 138, NCIC = 8;
    extern __shared__ unsigned short lds[];   // [138][256] = 70656 B

    const int tid  = threadIdx.x;
    const int wave = tid >> 6;
    const int lane = tid & 63;
    const int l15  = lane & 15;
    const int lhi  = lane >> 4;
    const int wr   = wave >> 2;               // t-half
    const int wc   = wave & 3;                // co-quarter
    const int b    = blockIdx.x >> 3;
    const int t0   = (blockIdx.x & 7) * 128;

    // ---- stage rows [t0-5, t0+133) (clamped; halo zeroed below) ----
    for (int r0 = wave * 2; r0 < ROWS; r0 += 16) {
        int r  = r0 + (lane >> 5);
        int gt = t0 - 5 + r;
        gt = gt < 0 ? 0 : (gt >= T_ ? T_ - 1 : gt);
        const unsigned short* src =
            Hin + ((size_t)b * T_ + gt) * CIN + (lane & 31) * 8;
        __builtin_amdgcn_global_load_lds(
            (const __attribute__((address_space(1))) void*)src,
            (__attribute__((address_space(3))) void*)&lds[r0 * CIN], 16, 0, 0);
    }
    __syncthreads();
    if (t0 == 0) {
        for (int u = tid; u < 5 * (CIN / 2); u += 512)
            ((unsigned*)lds)[u] = 0;                       // rows 0..4
    }
    if (t0 == T_ - 128) {
        for (int u = tid; u < 5 * (CIN / 2); u += 512)
            ((unsigned*)&lds[133 * CIN])[u] = 0;           // rows 133..137
    }
    __syncthreads();

    f32x4 acc[4][4];
#pragma unroll
    for (int tf = 0; tf < 4; ++tf)
#pragma unroll
        for (int n = 0; n < 4; ++n) acc[tf][n] = (f32x4){0.f, 0.f, 0.f, 0.f};

    const unsigned short* wpB = wpack + (size_t)(wc * 4) * 512 + lane * 8;
    const int arow = (wr * 64 + l15) * CIN;
    const int l153 = l15 + 3;

#define PREF(BUF, nkk)                                                         \
    {                                                                          \
        _Pragma("unroll") for (int n = 0; n < 4; ++n) BUF[n] =                 \
            *(const s16x8*)&wpB[(size_t)(nkk) * 8192 + n * 512];               \
    }

#define CMP(BUF, kk)                                                           \
    {                                                                          \
        const int k_ = (kk) % KW_;                                             \
        const int q_ = q0 + ((kk) / KW_) * 4;                                  \
        int key_ = (l153 + k_) & 7;                                            \
        int ao_  = arow + ((q_ ^ key_) << 3);                                  \
        s16x8 a0 = *(const s16x8*)&lds[ao_ + (0 * 16 + k_) * CIN];             \
        s16x8 a1 = *(const s16x8*)&lds[ao_ + (1 * 16 + k_) * CIN];             \
        s16x8 a2 = *(const s16x8*)&lds[ao_ + (2 * 16 + k_) * CIN];             \
        s16x8 a3 = *(const s16x8*)&lds[ao_ + (3 * 16 + k_) * CIN];             \
        __builtin_amdgcn_s_setprio(1);                                         \
        _Pragma("unroll") for (int n = 0; n < 4; ++n) {                        \
            bf16x8 bb = __builtin_bit_cast(bf16x8, BUF[n]);                    \
            acc[0][n] = __builtin_amdgcn_mfma_f32_16x16x32_bf16(               \
                __builtin_bit_cast(bf16x8, a0), bb, acc[0][n], 0, 0, 0);       \
            acc[1][n] = __builtin_amdgcn_mfma_f32_16x16x32_bf16(               \
                __builtin_bit_cast(bf16x8, a1), bb, acc[1][n], 0, 0, 0);       \
            acc[2][n] = __builtin_amdgcn_mfma_f32_16x16x32_bf16(               \
                __builtin_bit_cast(bf16x8, a2), bb, acc[2][n], 0, 0, 0);       \
            acc[3][n] = __builtin_amdgcn_mfma_f32_16x16x32_bf16(               \
                __builtin_bit_cast(bf16x8, a3), bb, acc[3][n], 0, 0, 0);       \
        }                                                                      \
        __builtin_amdgcn_s_setprio(0);                                         \
    }

    s16x8 Bf0[4], Bf1[4];
    PREF(Bf0, 0);
    const unsigned short* wpIt = wpB;
    int q0 = lhi;
#pragma unroll 1
    for (int cic2 = 0; cic2 < NCIC; cic2 += 2) {
#pragma unroll
        for (int kk = 0; kk < 2 * KW_; ++kk) {
            if ((kk & 1) == 0) {
                { _Pragma("unroll") for (int n = 0; n < 4; ++n) Bf1[n] =
                      *(const s16x8*)&wpIt[(size_t)(kk + 1) * 8192 + n * 512]; }
                CMP(Bf0, kk);
            } else {
                { _Pragma("unroll") for (int n = 0; n < 4; ++n) Bf0[n] =
                      *(const s16x8*)&wpIt[(size_t)(kk + 1) * 8192 + n * 512]; }
                CMP(Bf1, kk);
            }
        }
        wpIt += (size_t)2 * KW_ * 8192;
        q0 += 8;
    }
#undef PREF
#undef CMP

    if constexpr (!LAST) {
        // epilogue: bias + tanh -> bf16, stored chunk-swizzled by (t&7).
#pragma unroll
        for (int n = 0; n < 4; ++n) {
            int co = wc * 64 + n * 16 + l15;
            float bv = bias[co];
#pragma unroll
            for (int tf = 0; tf < 4; ++tf) {
#pragma unroll
                for (int r4 = 0; r4 < 4; ++r4) {
                    int t = t0 + wr * 64 + tf * 16 + lhi * 4 + r4;
                    float v = fast_tanh(acc[tf][n][r4] + bv);
                    int pos = (co >> 3) ^ (t & 7);
                    out[((size_t)b * T_ + t) * HID_ + pos * 8 + (co & 7)] = f2bf(v);
                }
            }
        }
    } else {
        // fused emissions: wave partial over its 64 co -> LDS -> reduce over wc
        float wv[4][NTAGS_], bvn[4];
#pragma unroll
        for (int n = 0; n < 4; ++n) {
            int co = wc * 64 + n * 16 + l15;
            bvn[n] = bias[co];
#pragma unroll
            for (int tg = 0; tg < NTAGS_; ++tg) wv[n][tg] = w_out[tg * HID_ + co];
        }
        __syncthreads();                 // A-tile reads done; reuse LDS
        float* pbuf = (float*)lds;       // [4 wc][128 t][8 tg] = 16 KB
#pragma unroll
        for (int tf = 0; tf < 4; ++tf) {
#pragma unroll
            for (int r4 = 0; r4 < 4; ++r4) {
                float h[4];
#pragma unroll
                for (int n = 0; n < 4; ++n)
                    h[n] = fast_tanh(acc[tf][n][r4] + bvn[n]);
                float pt[NTAGS_];
#pragma unroll
                for (int tg = 0; tg < NTAGS_; ++tg)
                    pt[tg] = h[0] * wv[0][tg] + h[1] * wv[1][tg] +
                             h[2] * wv[2][tg] + h[3] * wv[3][tg];
#pragma unroll
                for (int off = 8; off; off >>= 1)
#pragma unroll
                    for (int tg = 0; tg < NTAGS_; ++tg)
                        pt[tg] += __shfl_down(pt[tg], off);
                if (l15 == 0) {
                    int tloc = wr * 64 + tf * 16 + lhi * 4 + r4;
                    f32x4 lo = {pt[0], pt[1], pt[2], pt[3]};
                    f32x4 hi = {pt[4], pt[5], pt[6], pt[7]};
                    *(f32x4*)&pbuf[(wc * 128 + tloc) * 8]     = lo;
                    *(f32x4*)&pbuf[(wc * 128 + tloc) * 8 + 4] = hi;
                }
            }
        }
        __syncthreads();
        for (int u = tid; u < 128 * NTAGS_; u += 512) {
            float s = pbuf[u] + pbuf[1024 + u] + pbuf[2048 + u] + pbuf[3072 + u];
            emout[((size_t)b * T_ + t0) * NTAGS_ + u] = s;
        }
    }
}

// ---------------------------------------------------------------------------
// CRF segment kernel: wave per (b, s). Lane (i=lane>>3, j=lane&7) holds
// M[i][j], lse-product of S_t[i][j] = tr[i][j] + em[b,t,j] + bo[j].
// ---------------------------------------------------------------------------
__global__ __launch_bounds__(256)
void crf_seg_kernel(const float* __restrict__ em, const float* __restrict__ tr,
                    const float* __restrict__ bo, float* __restrict__ segM) {
    const int gw   = blockIdx.x * 4 + (threadIdx.x >> 6);
    const int b    = gw >> 5;
    const int s    = gw & 31;
    const int lane = threadIdx.x & 63;
    const int i    = lane >> 3;
    const int j    = lane & 7;
    const float* emb = em + (size_t)b * T_ * NTAGS_;
    const float boj = bo[j];

    float tc[8];
#pragma unroll
    for (int k = 0; k < 8; ++k) tc[k] = tr[k * 8 + j];

    const int tb = (s == 0) ? 1 : s * SEGL_;
    const int te = (s + 1) * SEGL_;

    float m = tr[i * 8 + j] + emb[tb * 8 + j] + boj;
    for (int t = tb + 1; t < te; ++t) {
        float emt = emb[t * 8 + j] + boj;
        float v[8];
#pragma unroll
        for (int k = 0; k < 8; ++k) v[k] = __shfl(m, (lane & 56) + k) + tc[k];
        float mx = fmaxf(fmaxf(fmaxf(v[0], v[1]), fmaxf(v[2], v[3])),
                         fmaxf(fmaxf(v[4], v[5]), fmaxf(v[6], v[7])));
        float sm = 0.f;
#pragma unroll
        for (int k = 0; k < 8; ++k) sm += __expf(v[k] - mx);
        m = mx + __logf(sm) + emt;
    }
    segM[(size_t)gw * 64 + lane] = m;
}

// ---------------------------------------------------------------------------
// CRF combine: one wave per batch. Numerator + 32-segment fold.
// ---------------------------------------------------------------------------
__global__ __launch_bounds__(64)
void crf_kernel(const float* __restrict__ em, const float* __restrict__ segM,
                const int* __restrict__ tags,
                const float* __restrict__ st, const float* __restrict__ et,
                const float* __restrict__ tr, const float* __restrict__ bo,
                float* __restrict__ outp) {
    __shared__ float sM[SEG_ * 64];
    const int b    = blockIdx.x;
    const int lane = threadIdx.x;
    const float* emb = em + (size_t)b * T_ * NTAGS_;
    const int*   tg  = tags + (size_t)b * T_;

    for (int u = lane; u < SEG_ * 64; u += 64)
        sM[u] = segM[(size_t)b * SEG_ * 64 + u];

    const float breg = bo[lane & 7];

    float num = 0.f;
    for (int t = 1 + lane; t < T_; t += 64) {
        int pt = tg[t - 1], ct = tg[t];
        num += tr[pt * NTAGS_ + ct] + emb[t * NTAGS_ + ct] + __shfl(breg, ct);
    }
#pragma unroll
    for (int off = 32; off; off >>= 1) num += __shfl_down(num, off);
    int tgf = tg[0], tgl = tg[T_ - 1];
    float bo_f = __shfl(breg, tgf);
    float score = 0.f;
    if (lane == 0)
        score = num + st[tgf] + emb[tgf] + bo_f + et[tgl];

    __syncthreads();

    const int j = lane & 7;
    float alpha = st[j] + emb[j] + breg;
    for (int sgm = 0; sgm < SEG_; ++sgm) {
        const float* M = &sM[sgm * 64];
        float v[8];
#pragma unroll
        for (int i = 0; i < 8; ++i) v[i] = __shfl(alpha, i) + M[i * 8 + j];
        float mx = fmaxf(fmaxf(fmaxf(v[0], v[1]), fmaxf(v[2], v[3])),
                         fmaxf(fmaxf(v[4], v[5]), fmaxf(v[6], v[7])));
        float sm = 0.f;
#pragma unroll
        for (int i = 0; i < 8; ++i) sm += __expf(v[i] - mx);
        alpha = mx + __logf(sm);
    }
    float vj = alpha + et[j];
    float w[8];
#pragma unroll
    for (int i = 0; i < 8; ++i) w[i] = __shfl(vj, i);
    float m2 = w[0];
#pragma unroll
    for (int i = 1; i < 8; ++i) m2 = fmaxf(m2, w[i]);
    float s2 = 0.f;
#pragma unroll
    for (int i = 0; i < 8; ++i) s2 += __expf(w[i] - m2);
    float log_z = m2 + __logf(s2);

    if (lane == 0) atomicAdd(outp, log_z - score);
}

// ---------------------------------------------------------------------------
extern "C" void kernel_launch(void* const* d_in, const int* in_sizes, int n_in,
                              void* d_out, int out_size, void* d_ws, size_t ws_size,
                              hipStream_t stream) {
    const float* x     = (const float*)d_in[0];
    const int*   tags  = (const int*)d_in[3];
    const float* w[5]  = {(const float*)d_in[4], (const float*)d_in[6],
                          (const float*)d_in[8], (const float*)d_in[10],
                          (const float*)d_in[12]};
    const float* bias[5] = {(const float*)d_in[5], (const float*)d_in[7],
                            (const float*)d_in[9], (const float*)d_in[11],
                            (const float*)d_in[13]};
    const float* w_out = (const float*)d_in[14];
    const float* b_out = (const float*)d_in[15];
    const float* st    = (const float*)d_in[16];
    const float* et    = (const float*)d_in[17];
    const float* tr    = (const float*)d_in[18];

    // workspace layout: H0, H1, wp tables, em, segM
    unsigned short* H0 = (unsigned short*)d_ws;
    unsigned short* H1 = H0 + (size_t)B_ * T_ * HID_;
    unsigned short* wpbase = H1 + (size_t)B_ * T_ * HID_;
    unsigned short* wp[5];
    wp[0] = wpbase;
    wp[1] = wp[0] + SZ0_;
    wp[2] = wp[1] + SZN_;
    wp[3] = wp[2] + SZN_;
    wp[4] = wp[3] + SZN_;
    float* em   = (float*)(wp[4] + SZN_);
    float* segM = em + (size_t)B_ * T_ * NTAGS_;
    // B-prefetch overruns a table by <=1 fragment group: wp[0..3] into the
    // next table, wp[4] into em (reads only, values never used).

    const int MLDS = 138 * 256 * 2;   // 70656 B dynamic LDS for mid convs
    hipFuncSetAttribute((const void*)conv_mid<false>,
                        hipFuncAttributeMaxDynamicSharedMemorySize, MLDS);
    hipFuncSetAttribute((const void*)conv_mid<true>,
                        hipFuncAttributeMaxDynamicSharedMemorySize, MLDS);

    pack_all<<<2048, 256, 0, stream>>>(w[0], w[1], w[2], w[3], w[4], wpbase);

    const int NBLK = B_ * (T_ / 128);   // 1024
    conv_first<<<NBLK, 512, 0, stream>>>(x, wp[0], bias[0], H0);

    conv_mid<false><<<NBLK, 512, MLDS, stream>>>(H0, wp[1], bias[1], H1,
                                                 nullptr, nullptr);
    conv_mid<false><<<NBLK, 512, MLDS, stream>>>(H1, wp[2], bias[2], H0,
                                                 nullptr, nullptr);
    conv_mid<false><<<NBLK, 512, MLDS, stream>>>(H0, wp[3], bias[3], H1,
                                                 nullptr, nullptr);
    conv_mid<true><<<NBLK, 512, MLDS, stream>>>(H1, wp[4], bias[4], nullptr,
                                                w_out, em);

    crf_seg_kernel<<<B_ * SEG_ / 4, 256, 0, stream>>>(em, tr, b_out, segM);

    hipMemsetAsync(d_out, 0, sizeof(float), stream);
    crf_kernel<<<B_, 64, 0, stream>>>(em, segM, tags, st, et, tr, b_out,
                                      (float*)d_out);
}

// Round 10
// 735.268 us; speedup vs baseline: 1.3109x; 1.0468x over previous
//
#include <hip/hip_runtime.h>

// DeepCNF: 5x conv1d(K=11)+tanh -> 1x1 conv to 8 tags -> CRF NLL (sum over batch).
// B=128 T=1024 IN=42 HID=256 K=11 NTAGS=8.
// Inter-layer H: bf16, row=(b*T+t)*256 shorts, 16B chunks at (chunk ^ (t&7)).
// Mid convs: 64t x 256co block, 4 waves (wc = co-quarter), 37.9KB LDS,
// __launch_bounds__(256,3) -> 3 blocks/CU (12 waves), 170-reg budget so BOTH
// A and B are double-buffered in registers: per it, issue B(it+1) + A(it+1)
// ds_reads, then the 16-MFMA cluster of it covers both latencies.
// conv4 fuses the emission projection via LDS partial reduce (no atomics).
// CRF: log-semiring segment matrix products (32 segments of 32 steps).

#define B_ 128
#define T_ 1024
#define IN_DIM_ 42
#define HID_ 256
#define KW_ 11
#define NTAGS_ 8
#define SEG_ 32
#define SEGL_ (T_ / SEG_)   // 32

typedef __bf16 bf16x8 __attribute__((ext_vector_type(8)));
typedef float f32x4 __attribute__((ext_vector_type(4)));
typedef short s16x8 __attribute__((ext_vector_type(8)));

__device__ __forceinline__ unsigned short f2bf(float f) {
    unsigned u = __builtin_bit_cast(unsigned, f);
    u += 0x7FFFu + ((u >> 16) & 1u);   // RNE
    return (unsigned short)(u >> 16);
}
__device__ __forceinline__ float fast_tanh(float x) {
    float e = __expf(2.f * x);          // inf/0 saturate to +-1 correctly
    return 1.f - 2.f / (e + 1.f);
}

#define SZ0_ (KW_ * 2 * 16 * 512)   // layer0 table (k-major)
#define SZN_ (KW_ * 8 * 16 * 512)   // layers1-4 tables (cic-major)

// ---------------------------------------------------------------------------
// Pack all conv weights fp32 -> bf16 16x16-MFMA B-fragments.
// Layer 0 (k-major, it2 = k*2+cic):   wp[((it2*16+coc)*64+lane)*8+e]
// Layers 1-4 (cic-major, it=cic*11+k): wp[((it*16+coc)*64+lane)*8+e]
//   = w[coc*16+(l&15)][cic*32+((l>>4)&3)*8+e][k]
// ---------------------------------------------------------------------------
__global__ void pack_all(const float* __restrict__ w0, const float* __restrict__ w1,
                         const float* __restrict__ w2, const float* __restrict__ w3,
                         const float* __restrict__ w4, unsigned short* __restrict__ wp) {
    const int total = SZ0_ + 4 * SZN_;
    for (int idx = blockIdx.x * 256 + threadIdx.x; idx < total;
         idx += gridDim.x * 256) {
        float v;
        if (idx < SZ0_) {
            int loc = idx;
            int it2 = loc >> 13;
            int cic = it2 & 1, k = it2 >> 1;
            int e    = loc & 7;
            int lane = (loc >> 3) & 63;
            int coc  = (loc >> 9) & 15;
            int co = coc * 16 + (lane & 15);
            int ci = cic * 32 + ((lane >> 4) & 3) * 8 + e;
            v = (ci < IN_DIM_) ? w0[(co * IN_DIM_ + ci) * KW_ + k] : 0.f;
        } else {
            int r = idx - SZ0_;
            int L = r / SZN_;
            int loc = r - L * SZN_;
            const float* w = (L == 0) ? w1 : (L == 1) ? w2 : (L == 2) ? w3 : w4;
            int e    = loc & 7;
            int lane = (loc >> 3) & 63;
            int coc  = (loc >> 9) & 15;
            int rest = loc >> 13;          // it = cic*KW_ + k
            int cic  = rest / KW_;
            int k    = rest - cic * KW_;
            int co = coc * 16 + (lane & 15);
            int ci = cic * 32 + ((lane >> 4) & 3) * 8 + e;
            v = w[(co * HID_ + ci) * KW_ + k];
        }
        wp[idx] = f2bf(v);
    }
}

// ---------------------------------------------------------------------------
// First conv layer: fp32 x (42ch) input, 128t x 256co block, 8 waves
// (2 t-halves x 4 co-quarters), 16x16x32 MFMA, CIN padded to 64.
// ---------------------------------------------------------------------------
__global__ __launch_bounds__(512, 4)
void conv_first(const float* __restrict__ x, const unsigned short* __restrict__ wpack,
                const float* __restrict__ bias, unsigned short* __restrict__ out) {
    constexpr int CIN = 64, ROWS = 138;
    __shared__ unsigned short lds[ROWS * CIN];

    const int tid  = threadIdx.x;
    const int wave = tid >> 6;
    const int lane = tid & 63;
    const int l15  = lane & 15;
    const int lhi  = lane >> 4;
    const int wr   = wave >> 2;
    const int wc   = wave & 3;
    const int b    = blockIdx.x >> 3;
    const int t0   = (blockIdx.x & 7) * 128;

    for (int u = tid; u < ROWS * 32; u += 512) {
        int r = u >> 5, m = u & 31;        // m = float2 index, ci0 = 2m
        int gt = t0 - 5 + r;
        unsigned val = 0;
        if (gt >= 0 && gt < T_ && 2 * m < IN_DIM_) {
            float2 f = *(const float2*)&x[((size_t)b * T_ + gt) * IN_DIM_ + 2 * m];
            val = (unsigned)f2bf(f.x) | ((unsigned)f2bf(f.y) << 16);
        }
        int c = m >> 2;
        int p = c ^ ((r + 3) & 7);
        ((unsigned*)lds)[(r * CIN + p * 8) / 2 + (m & 3)] = val;
    }
    __syncthreads();

    f32x4 acc[4][4];
#pragma unroll
    for (int tf = 0; tf < 4; ++tf)
#pragma unroll
        for (int n = 0; n < 4; ++n) acc[tf][n] = (f32x4){0.f, 0.f, 0.f, 0.f};

    const unsigned short* wpq = wpack + (size_t)(wc * 4) * 512 + lane * 8;
    const int arow = (wr * 64 + l15) * CIN;
    const int l153 = l15 + 3;

    s16x8 Bq[2][4];
#pragma unroll
    for (int n = 0; n < 4; ++n) Bq[0][n] = *(const s16x8*)&wpq[n * 512];

#pragma unroll
    for (int k = 0; k < KW_; ++k) {
#pragma unroll
        for (int cic = 0; cic < 2; ++cic) {
            const int it2 = k * 2 + cic;
            const int nxt = it2 + 1;       // overrun into next table: harmless
#pragma unroll
            for (int n = 0; n < 4; ++n)
                Bq[nxt & 1][n] = *(const s16x8*)&wpq[(size_t)nxt * 8192 + n * 512];
            const int key = (l153 + k) & 7;
            const int ao  = arow + (((cic * 4 + lhi) ^ key) << 3);
            s16x8 a0 = *(const s16x8*)&lds[ao + (0 * 16 + k) * CIN];
            s16x8 a1 = *(const s16x8*)&lds[ao + (1 * 16 + k) * CIN];
            s16x8 a2 = *(const s16x8*)&lds[ao + (2 * 16 + k) * CIN];
            s16x8 a3 = *(const s16x8*)&lds[ao + (3 * 16 + k) * CIN];
            __builtin_amdgcn_s_setprio(1);
#pragma unroll
            for (int n = 0; n < 4; ++n) {
                bf16x8 bb = __builtin_bit_cast(bf16x8, Bq[it2 & 1][n]);
                acc[0][n] = __builtin_amdgcn_mfma_f32_16x16x32_bf16(
                    __builtin_bit_cast(bf16x8, a0), bb, acc[0][n], 0, 0, 0);
                acc[1][n] = __builtin_amdgcn_mfma_f32_16x16x32_bf16(
                    __builtin_bit_cast(bf16x8, a1), bb, acc[1][n], 0, 0, 0);
                acc[2][n] = __builtin_amdgcn_mfma_f32_16x16x32_bf16(
                    __builtin_bit_cast(bf16x8, a2), bb, acc[2][n], 0, 0, 0);
                acc[3][n] = __builtin_amdgcn_mfma_f32_16x16x32_bf16(
                    __builtin_bit_cast(bf16x8, a3), bb, acc[3][n], 0, 0, 0);
            }
            __builtin_amdgcn_s_setprio(0);
        }
    }

#pragma unroll
    for (int n = 0; n < 4; ++n) {
        int co = wc * 64 + n * 16 + l15;
        float bv = bias[co];
#pragma unroll
        for (int tf = 0; tf < 4; ++tf) {
#pragma unroll
            for (int r4 = 0; r4 < 4; ++r4) {
                int t = t0 + wr * 64 + tf * 16 + lhi * 4 + r4;
                float v = fast_tanh(acc[tf][n][r4] + bv);
                int pos = (co >> 3) ^ (t & 7);
                out[((size_t)b * T_ + t) * HID_ + pos * 8 + (co & 7)] = f2bf(v);
            }
        }
    }
}

// ---------------------------------------------------------------------------
// Mid conv: 64t x 256co block, 4 waves (wc = wave = co-quarter), wave tile
// 64t x 64co, 16x16x32 MFMA. A-dbuf + B-dbuf register prefetch (it+1 issued
// before cluster(it)). launch_bounds(256,3): 12 waves/CU, <=170 regs.
// LAST: fused emission projection via LDS partial reduce (no atomics).
// ---------------------------------------------------------------------------
template <bool LAST>
__global__ __launch_bounds__(256, 3)
void conv_mid(const unsigned short* __restrict__ Hin,
              const unsigned short* __restrict__ wpack,
              const float* __restrict__ bias, unsigned short* __restrict__ out,
              const float* __restrict__ w_out, float* __restrict__ emout) {
    constexpr int CIN = 256, ROWS = 74, NCIC = 8;
    extern __shared__ unsigned short lds[];   // [74][256] = 37888 B

    const int tid  = threadIdx.x;
    const int wave = tid >> 6;
    const int lane = tid & 63;
    const int l15  = lane & 15;
    const int lhi  = lane >> 4;
    const int wc   = wave;                    // co-quarter
    const int b    = blockIdx.x >> 4;
    const int t0   = (blockIdx.x & 15) * 64;

    // ---- stage rows [t0-5, t0+69) (clamped; halo zeroed below) ----
    for (int r0 = wave * 2; r0 < ROWS; r0 += 8) {
        int r  = r0 + (lane >> 5);
        int gt = t0 - 5 + r;
        gt = gt < 0 ? 0 : (gt >= T_ ? T_ - 1 : gt);
        const unsigned short* src =
            Hin + ((size_t)b * T_ + gt) * CIN + (lane & 31) * 8;
        __builtin_amdgcn_global_load_lds(
            (const __attribute__((address_space(1))) void*)src,
            (__attribute__((address_space(3))) void*)&lds[r0 * CIN], 16, 0, 0);
    }
    __syncthreads();
    if (t0 == 0) {
        for (int u = tid; u < 5 * (CIN / 2); u += 256)
            ((unsigned*)lds)[u] = 0;                       // rows 0..4
    }
    if (t0 == T_ - 64) {
        for (int u = tid; u < 5 * (CIN / 2); u += 256)
            ((unsigned*)&lds[69 * CIN])[u] = 0;            // rows 69..73
    }
    __syncthreads();

    f32x4 acc[4][4];
#pragma unroll
    for (int tf = 0; tf < 4; ++tf)
#pragma unroll
        for (int n = 0; n < 4; ++n) acc[tf][n] = (f32x4){0.f, 0.f, 0.f, 0.f};

    const unsigned short* wpIt = wpack + (size_t)(wc * 4) * 512 + lane * 8;
    const int arow = l15 * CIN;
    const int l153 = l15 + 3;

    s16x8 Aa[4], Ab[4], Bf0[4], Bf1[4];

#define PREF_B(BUF, nkk)                                                       \
    {                                                                          \
        _Pragma("unroll") for (int n = 0; n < 4; ++n) BUF[n] =                 \
            *(const s16x8*)&wpIt[(size_t)(nkk) * 8192 + n * 512];              \
    }
    // A fragment for relative iteration kkn (0..22) within current cic2 pair:
    // cic offset = kkn/11, k = kkn%11.
#define PREF_A(BUF, kkn)                                                       \
    {                                                                          \
        const int co_ = (kkn) / KW_;                                           \
        const int kn_ = (kkn) - co_ * KW_;                                     \
        const int key_ = (l153 + kn_) & 7;                                     \
        const int ao_  = arow + (((q0 + co_ * 4) ^ key_) << 3);                \
        BUF[0] = *(const s16x8*)&lds[ao_ + (0 * 16 + kn_) * CIN];              \
        BUF[1] = *(const s16x8*)&lds[ao_ + (1 * 16 + kn_) * CIN];              \
        BUF[2] = *(const s16x8*)&lds[ao_ + (2 * 16 + kn_) * CIN];              \
        BUF[3] = *(const s16x8*)&lds[ao_ + (3 * 16 + kn_) * CIN];              \
    }
#define CMP(AB, BB)                                                            \
    {                                                                          \
        __builtin_amdgcn_s_setprio(1);                                         \
        _Pragma("unroll") for (int n = 0; n < 4; ++n) {                        \
            bf16x8 bb = __builtin_bit_cast(bf16x8, BB[n]);                     \
            acc[0][n] = __builtin_amdgcn_mfma_f32_16x16x32_bf16(               \
                __builtin_bit_cast(bf16x8, AB[0]), bb, acc[0][n], 0, 0, 0);    \
            acc[1][n] = __builtin_amdgcn_mfma_f32_16x16x32_bf16(               \
                __builtin_bit_cast(bf16x8, AB[1]), bb, acc[1][n], 0, 0, 0);    \
            acc[2][n] = __builtin_amdgcn_mfma_f32_16x16x32_bf16(               \
                __builtin_bit_cast(bf16x8, AB[2]), bb, acc[2][n], 0, 0, 0);    \
            acc[3][n] = __builtin_amdgcn_mfma_f32_16x16x32_bf16(               \
                __builtin_bit_cast(bf16x8, AB[3]), bb, acc[3][n], 0, 0, 0);    \
        }                                                                      \
        __builtin_amdgcn_s_setprio(0);                                         \
    }

    int q0 = lhi;                // chunk base = cic2*4 + lhi
    PREF_B(Bf0, 0);
    PREF_A(Aa, 0);
#pragma unroll 1
    for (int cic2 = 0; cic2 < NCIC; cic2 += 2) {
#pragma unroll
        for (int kk = 0; kk < 2 * KW_; ++kk) {
            if ((kk & 1) == 0) {
                PREF_B(Bf1, kk + 1);     // kk==21 case handled by odd branch
                PREF_A(Ab, kk + 1);
                CMP(Aa, Bf0);
            } else {
                PREF_B(Bf0, kk + 1);     // kk+1==22 -> next cic2 group it0
                PREF_A(Aa, kk + 1);      // (q0+8, k=0) == next group's first
                CMP(Ab, Bf1);
            }
        }
        wpIt += (size_t)2 * KW_ * 8192;
        q0 += 8;
        // final group's trailing prefetch reads garbage in-bounds / table
        // overrun (into em buffer) -- loaded but never consumed.
    }
#undef PREF_B
#undef PREF_A
#undef CMP

    if constexpr (!LAST) {
        // epilogue: bias + tanh -> bf16, stored chunk-swizzled by (t&7).
#pragma unroll
        for (int n = 0; n < 4; ++n) {
            int co = wc * 64 + n * 16 + l15;
            float bv = bias[co];
#pragma unroll
            for (int tf = 0; tf < 4; ++tf) {
#pragma unroll
                for (int r4 = 0; r4 < 4; ++r4) {
                    int t = t0 + tf * 16 + lhi * 4 + r4;
                    float v = fast_tanh(acc[tf][n][r4] + bv);
                    int pos = (co >> 3) ^ (t & 7);
                    out[((size_t)b * T_ + t) * HID_ + pos * 8 + (co & 7)] = f2bf(v);
                }
            }
        }
    } else {
        // fused emissions: wave partial over its 64 co -> LDS -> reduce over wc
        float wv[4][NTAGS_], bvn[4];
#pragma unroll
        for (int n = 0; n < 4; ++n) {
            int co = wc * 64 + n * 16 + l15;
            bvn[n] = bias[co];
#pragma unroll
            for (int tg = 0; tg < NTAGS_; ++tg) wv[n][tg] = w_out[tg * HID_ + co];
        }
        __syncthreads();                 // A-tile reads done; reuse LDS
        float* pbuf = (float*)lds;       // [4 wc][64 t][8 tg] = 8 KB
#pragma unroll
        for (int tf = 0; tf < 4; ++tf) {
#pragma unroll
            for (int r4 = 0; r4 < 4; ++r4) {
                float h[4];
#pragma unroll
                for (int n = 0; n < 4; ++n)
                    h[n] = fast_tanh(acc[tf][n][r4] + bvn[n]);
                float pt[NTAGS_];
#pragma unroll
                for (int tg = 0; tg < NTAGS_; ++tg)
                    pt[tg] = h[0] * wv[0][tg] + h[1] * wv[1][tg] +
                             h[2] * wv[2][tg] + h[3] * wv[3][tg];
#pragma unroll
                for (int off = 8; off; off >>= 1)
#pragma unroll
                    for (int tg = 0; tg < NTAGS_; ++tg)
                        pt[tg] += __shfl_down(pt[tg], off);
                if (l15 == 0) {
                    int tloc = tf * 16 + lhi * 4 + r4;
                    f32x4 lo = {pt[0], pt[1], pt[2], pt[3]};
                    f32x4 hi = {pt[4], pt[5], pt[6], pt[7]};
                    *(f32x4*)&pbuf[(wc * 64 + tloc) * 8]     = lo;
                    *(f32x4*)&pbuf[(wc * 64 + tloc) * 8 + 4] = hi;
                }
            }
        }
        __syncthreads();
        for (int u = tid; u < 64 * NTAGS_; u += 256) {
            float s = pbuf[u] + pbuf[512 + u] + pbuf[1024 + u] + pbuf[1536 + u];
            emout[((size_t)b * T_ + t0) * NTAGS_ + u] = s;
        }
    }
}

// ---------------------------------------------------------------------------
// CRF segment kernel: wave per (b, s). Lane (i=lane>>3, j=lane&7) holds
// M[i][j], lse-product of S_t[i][j] = tr[i][j] + em[b,t,j] + bo[j].
// ---------------------------------------------------------------------------
__global__ __launch_bounds__(256)
void crf_seg_kernel(const float* __restrict__ em, const float* __restrict__ tr,
                    const float* __restrict__ bo, float* __restrict__ segM) {
    const int gw   = blockIdx.x * 4 + (threadIdx.x >> 6);
    const int b    = gw >> 5;
    const int s    = gw & 31;
    const int lane = threadIdx.x & 63;
    const int i    = lane >> 3;
    const int j    = lane & 7;
    const float* emb = em + (size_t)b * T_ * NTAGS_;
    const float boj = bo[j];

    float tc[8];
#pragma unroll
    for (int k = 0; k < 8; ++k) tc[k] = tr[k * 8 + j];

    const int tb = (s == 0) ? 1 : s * SEGL_;
    const int te = (s + 1) * SEGL_;

    float m = tr[i * 8 + j] + emb[tb * 8 + j] + boj;
    for (int t = tb + 1; t < te; ++t) {
        float emt = emb[t * 8 + j] + boj;
        float v[8];
#pragma unroll
        for (int k = 0; k < 8; ++k) v[k] = __shfl(m, (lane & 56) + k) + tc[k];
        float mx = fmaxf(fmaxf(fmaxf(v[0], v[1]), fmaxf(v[2], v[3])),
                         fmaxf(fmaxf(v[4], v[5]), fmaxf(v[6], v[7])));
        float sm = 0.f;
#pragma unroll
        for (int k = 0; k < 8; ++k) sm += __expf(v[k] - mx);
        m = mx + __logf(sm) + emt;
    }
    segM[(size_t)gw * 64 + lane] = m;
}

// ---------------------------------------------------------------------------
// CRF combine: one wave per batch. Numerator + 32-segment fold.
// ---------------------------------------------------------------------------
__global__ __launch_bounds__(64)
void crf_kernel(const float* __restrict__ em, const float* __restrict__ segM,
                const int* __restrict__ tags,
                const float* __restrict__ st, const float* __restrict__ et,
                const float* __restrict__ tr, const float* __restrict__ bo,
                float* __restrict__ outp) {
    __shared__ float sM[SEG_ * 64];
    const int b    = blockIdx.x;
    const int lane = threadIdx.x;
    const float* emb = em + (size_t)b * T_ * NTAGS_;
    const int*   tg  = tags + (size_t)b * T_;

    for (int u = lane; u < SEG_ * 64; u += 64)
        sM[u] = segM[(size_t)b * SEG_ * 64 + u];

    const float breg = bo[lane & 7];

    float num = 0.f;
    for (int t = 1 + lane; t < T_; t += 64) {
        int pt = tg[t - 1], ct = tg[t];
        num += tr[pt * NTAGS_ + ct] + emb[t * NTAGS_ + ct] + __shfl(breg, ct);
    }
#pragma unroll
    for (int off = 32; off; off >>= 1) num += __shfl_down(num, off);
    int tgf = tg[0], tgl = tg[T_ - 1];
    float bo_f = __shfl(breg, tgf);
    float score = 0.f;
    if (lane == 0)
        score = num + st[tgf] + emb[tgf] + bo_f + et[tgl];

    __syncthreads();

    const int j = lane & 7;
    float alpha = st[j] + emb[j] + breg;
    for (int sgm = 0; sgm < SEG_; ++sgm) {
        const float* M = &sM[sgm * 64];
        float v[8];
#pragma unroll
        for (int i = 0; i < 8; ++i) v[i] = __shfl(alpha, i) + M[i * 8 + j];
        float mx = fmaxf(fmaxf(fmaxf(v[0], v[1]), fmaxf(v[2], v[3])),
                         fmaxf(fmaxf(v[4], v[5]), fmaxf(v[6], v[7])));
        float sm = 0.f;
#pragma unroll
        for (int i = 0; i < 8; ++i) sm += __expf(v[i] - mx);
        alpha = mx + __logf(sm);
    }
    float vj = alpha + et[j];
    float w[8];
#pragma unroll
    for (int i = 0; i < 8; ++i) w[i] = __shfl(vj, i);
    float m2 = w[0];
#pragma unroll
    for (int i = 1; i < 8; ++i) m2 = fmaxf(m2, w[i]);
    float s2 = 0.f;
#pragma unroll
    for (int i = 0; i < 8; ++i) s2 += __expf(w[i] - m2);
    float log_z = m2 + __logf(s2);

    if (lane == 0) atomicAdd(outp, log_z - score);
}

// ---------------------------------------------------------------------------
extern "C" void kernel_launch(void* const* d_in, const int* in_sizes, int n_in,
                              void* d_out, int out_size, void* d_ws, size_t ws_size,
                              hipStream_t stream) {
    const float* x     = (const float*)d_in[0];
    const int*   tags  = (const int*)d_in[3];
    const float* w[5]  = {(const float*)d_in[4], (const float*)d_in[6],
                          (const float*)d_in[8], (const float*)d_in[10],
                          (const float*)d_in[12]};
    const float* bias[5] = {(const float*)d_in[5], (const float*)d_in[7],
                            (const float*)d_in[9], (const float*)d_in[11],
                            (const float*)d_in[13]};
    const float* w_out = (const float*)d_in[14];
    const float* b_out = (const float*)d_in[15];
    const float* st    = (const float*)d_in[16];
    const float* et    = (const float*)d_in[17];
    const float* tr    = (const float*)d_in[18];

    // workspace layout: H0, H1, wp tables, em, segM
    unsigned short* H0 = (unsigned short*)d_ws;
    unsigned short* H1 = H0 + (size_t)B_ * T_ * HID_;
    unsigned short* wpbase = H1 + (size_t)B_ * T_ * HID_;
    unsigned short* wp[5];
    wp[0] = wpbase;
    wp[1] = wp[0] + SZ0_;
    wp[2] = wp[1] + SZN_;
    wp[3] = wp[2] + SZN_;
    wp[4] = wp[3] + SZN_;
    float* em   = (float*)(wp[4] + SZN_);
    float* segM = em + (size_t)B_ * T_ * NTAGS_;
    // B-prefetch overruns a table by <=1 fragment group: wp[0..3] into the
    // next table, wp[4] into em (reads only, values never consumed).

    pack_all<<<2048, 256, 0, stream>>>(w[0], w[1], w[2], w[3], w[4], wpbase);

    conv_first<<<B_ * (T_ / 128), 512, 0, stream>>>(x, wp[0], bias[0], H0);

    const int NBLK = B_ * (T_ / 64);   // 2048
    const int MLDS = 74 * 256 * 2;     // 37888 B
    conv_mid<false><<<NBLK, 256, MLDS, stream>>>(H0, wp[1], bias[1], H1,
                                                 nullptr, nullptr);
    conv_mid<false><<<NBLK, 256, MLDS, stream>>>(H1, wp[2], bias[2], H0,
                                                 nullptr, nullptr);
    conv_mid<false><<<NBLK, 256, MLDS, stream>>>(H0, wp[3], bias[3], H1,
                                                 nullptr, nullptr);
    conv_mid<true><<<NBLK, 256, MLDS, stream>>>(H1, wp[4], bias[4], nullptr,
                                                w_out, em);

    crf_seg_kernel<<<B_ * SEG_ / 4, 256, 0, stream>>>(em, tr, b_out, segM);

    hipMemsetAsync(d_out, 0, sizeof(float), stream);
    crf_kernel<<<B_, 64, 0, stream>>>(em, segM, tags, st, et, tr, b_out,
                                      (float*)d_out);
}